// Round 5
// baseline (354.968 us; speedup 1.0000x reference)
//
#include <hip/hip_runtime.h>
#include <stdint.h>

#define C_   128
#define HW_  16384
#define CHW_ (C_*HW_)
#define N_   65536
#define E_   11
#define K_   6
#define HID_ 512

typedef __attribute__((ext_vector_type(8))) _Float16 half8;
typedef __attribute__((ext_vector_type(2))) _Float16 h2;
typedef __attribute__((ext_vector_type(2))) __fp16 fp16v2;
typedef __attribute__((ext_vector_type(16))) float float16v;
typedef __attribute__((ext_vector_type(2))) unsigned uint2v;

// async global->LDS, 16B per lane; LDS dst is wave-uniform base + lane*16
#define GLD(g, s) __builtin_amdgcn_global_load_lds( \
    (const __attribute__((address_space(1))) unsigned int*)(uintptr_t)(g), \
    (__attribute__((address_space(3))) unsigned int*)(unsigned int)(uintptr_t)(s), 16, 0, 0)

// f32x2 -> packed f16 pair (RTZ), bitcast to _Float16 vector
__device__ __forceinline__ h2 pkrtz(float a, float b){
  union { fp16v2 f; h2 h; } u;
  u.f = __builtin_amdgcn_cvt_pkrtz(a, b);
  return u.h;
}
// gelu(v)*wr on packed f16 pairs: odd deg-7 erf fit (|t|<=2.5, max err ~2.4e-3).
__device__ __forceinline__ h2 gelu2h(h2 v, h2 wr2){
  h2 u = v * v;
  h2 s = u * (h2)(_Float16)(-0.00076957f) + (h2)(_Float16)(0.0147811f);
  s = s * u + (h2)(_Float16)(-0.126434f);
  s = s * u + (h2)(_Float16)(0.795742f);
  h2 p = v * s;
  h2 phi = p * (h2)(_Float16)(0.5f) + (h2)(_Float16)(0.5f);
  return v * wr2 * phi;
}
// lane l <-> lane l^32 exchange: a' = [a_lo, b_lo], b' = [a_hi, b_hi]
__device__ __forceinline__ void pswap32(unsigned &a, unsigned &b){
#if __has_builtin(__builtin_amdgcn_permlane32_swap)
  uint2v r = __builtin_amdgcn_permlane32_swap(a, b, false, false);
  a = r.x; b = r.y;
#else
  asm volatile("v_permlane32_swap_b32 %0, %1" : "+v"(a), "+v"(b));
#endif
}

// ---------------- build MFMA-frag-ordered f16 weight image (32x32x16 frags) ----
// record i = e*16+hc (16KB): [0,8KB) W1 A-frags kc=0..7: lane l holds
//   w1[e][hc*32+(l&31)][kc*16+(l>>5)*8 + j], j=0..7
// [8KB,16KB): W2 A-frags (ct*2+kc2): lane l: w2[e][ct*32+(l&31)][hc*32+kc2*16+(l>>5)*8+j]
// plus b1h image: per record 32 f16 in hacc-register order (j-order, hi-major).
__global__ __launch_bounds__(256) void k_convert(const float* __restrict__ w1,
                                                 const float* __restrict__ w2,
                                                 const float* __restrict__ b1,
                                                 unsigned short* __restrict__ wimg,
                                                 unsigned short* __restrict__ b1h,
                                                 float* __restrict__ auxsum){
  int t = blockIdx.x * 256 + threadIdx.x;
  if (t < 23) auxsum[t] = 0.0f;          // 22 aux accumulators + b2nz flag
  if (t >= 185856) return;
  if (t >= 180224){                       // b1h: 176 recs x 32 f16
    int t2 = t - 180224;
    int rec = t2 >> 5, j5 = t2 & 31;
    int hi = j5 >> 4, j = j5 & 15;
    int e = rec >> 4, hc = rec & 15;
    int row = (j & 3) + 8 * (j >> 2) + 4 * hi;
    union { _Float16 h; unsigned short u; } cv;
    cv.h = (_Float16)b1[e * 512 + hc * 32 + row];
    b1h[rec * 32 + j5] = cv.u;
    return;
  }
  const float* src;
  size_t dst;
  if (t < 90112){
    int e = t >> 13, hid = (t >> 4) & 511, c8 = t & 15;
    src = w1 + (size_t)t * 8;
    int rec = e * 16 + (hid >> 5);
    int kc = c8 >> 1, half = c8 & 1;
    int l = (hid & 31) | (half << 5);
    dst = (size_t)rec * 8192 + kc * 512 + l * 8;
  } else {
    int u = t - 90112;
    int e = u >> 13, cc = (u >> 6) & 127, hd8 = u & 63;
    src = w2 + (size_t)u * 8;
    int rec = e * 16 + (hd8 >> 2);
    int kc2 = (hd8 >> 1) & 1, half = hd8 & 1, ct = cc >> 5;
    int l = (cc & 31) | (half << 5);
    dst = (size_t)rec * 8192 + 4096 + (ct * 2 + kc2) * 512 + l * 8;
  }
  float4 a = *(const float4*)src, b = *(const float4*)(src + 4);
  union { _Float16 h[8]; uint4 v; } u4;
  u4.h[0] = (_Float16)a.x; u4.h[1] = (_Float16)a.y;
  u4.h[2] = (_Float16)a.z; u4.h[3] = (_Float16)a.w;
  u4.h[4] = (_Float16)b.x; u4.h[5] = (_Float16)b.y;
  u4.h[6] = (_Float16)b.z; u4.h[7] = (_Float16)b.w;
  *(uint4*)(wimg + dst) = u4.v;
}

// ---------------- fused: NCHW->channels-last f16 transpose + router ----------------
__global__ __launch_bounds__(256) void k_pre(const float* __restrict__ x,
                                             const float* __restrict__ gw,
                                             const float* __restrict__ gb,
                                             const float* __restrict__ b2,
                                             unsigned short* __restrict__ xcl,
                                             float* __restrict__ mask,
                                             float* __restrict__ auxsum){
  __shared__ __align__(16) float tt[64 * 130];
  __shared__ __align__(16) float g[E_ * C_];
  __shared__ float gbs[E_];
  __shared__ float ap[E_], al[E_];
  int tid = threadIdx.x;
  int pix0 = blockIdx.x * 64;
  int b = pix0 >> 14, hw0 = pix0 & 16383;
  const float* xb = x + (size_t)b * CHW_ + hw0;

  for (int i = tid; i < E_ * C_; i += 256) g[i] = gw[i];
  if (tid < E_) { gbs[tid] = gb[tid]; ap[tid] = 0.f; al[tid] = 0.f; }

  // float4 loads along the contiguous p axis: 4x fewer global trips than scalar
  #pragma unroll
  for (int it = 0; it < 8; ++it){
    int flat = it * 256 + tid;          // 2048 quads = 128 c x 16 quads-of-p
    int c = flat >> 4, p4 = (flat & 15) << 2;
    float4 v = *(const float4*)(xb + (size_t)c * HW_ + p4);
    tt[(p4 + 0) * 130 + c] = v.x;
    tt[(p4 + 1) * 130 + c] = v.y;
    tt[(p4 + 2) * 130 + c] = v.z;
    tt[(p4 + 3) * 130 + c] = v.w;
  }
  __syncthreads();
  #pragma unroll 4
  for (int it = 0; it < 16; ++it){
    int u = it * 256 + tid;
    int p = u >> 6, cc = u & 63;
    float f0 = tt[p * 130 + 2 * cc], f1 = tt[p * 130 + 2 * cc + 1];
    union { h2 h; unsigned u; } pv;
    pv.h = pkrtz(f0, f1);
    ((unsigned*)xcl)[(size_t)(pix0 + p) * 64 + cc] = pv.u;
  }

  // router: 4 threads per pixel (same wave quad), each 32 channels, float2 reads
  int p = tid >> 2, t4 = tid & 3;
  float lg[E_];
  #pragma unroll
  for (int e = 0; e < E_; ++e) lg[e] = (t4 == 0) ? gbs[e] : 0.f;
  const float2* ttrow = (const float2*)(tt + p * 130 + t4 * 32);
  #pragma unroll 4
  for (int j2 = 0; j2 < 16; ++j2){
    float2 xv = ttrow[j2];
    #pragma unroll
    for (int e = 0; e < E_; ++e){
      float2 gv = *(const float2*)(g + e * C_ + t4 * 32 + j2 * 2);
      lg[e] = fmaf(xv.x, gv.x, lg[e]);
      lg[e] = fmaf(xv.y, gv.y, lg[e]);
    }
  }
  #pragma unroll
  for (int e = 0; e < E_; ++e){
    lg[e] += __shfl_xor(lg[e], 1, 64);
    lg[e] += __shfl_xor(lg[e], 2, 64);
  }
  float mx = lg[0];
  #pragma unroll
  for (int e = 1; e < E_; ++e) mx = fmaxf(mx, lg[e]);
  float pr[E_]; float s = 0.f;
  #pragma unroll
  for (int e = 0; e < E_; ++e){ pr[e] = expf(lg[e] - mx); s += pr[e]; }
  float inv = 1.0f / s;
  #pragma unroll
  for (int e = 0; e < E_; ++e) pr[e] *= inv;

  unsigned selmask = 0; float wsum = 0.f;
  for (int k = 0; k < K_; ++k){
    float bv = -1.f; int bi = 0;
    #pragma unroll
    for (int e = 0; e < E_; ++e){
      bool better = (((selmask >> e) & 1u) == 0u) && (pr[e] > bv);
      bv = better ? pr[e] : bv;
      bi = better ? e : bi;
    }
    selmask |= 1u << bi; wsum += bv;
  }
  float invw = 1.0f / wsum;
  if (t4 == 0){
    int pix = pix0 + p;
    #pragma unroll
    for (int e = 0; e < E_; ++e){
      bool sel = (selmask >> e) & 1u;
      mask[(size_t)pix * E_ + e] = sel ? pr[e] * invw : 0.f;
      atomicAdd(&ap[e], pr[e]);
      if (sel) atomicAdd(&al[e], 1.0f);
    }
  }
  __syncthreads();
  if (tid < E_){
    atomicAdd(&auxsum[tid], ap[tid]);
    atomicAdd(&auxsum[E_ + tid], al[tid]);
  }
  // b2 nonzero flag (block 0 only; k_ffn runs after all k_pre blocks)
  if (blockIdx.x == 0 && tid < 64){
    int nz = 0;
    for (int idx = tid; idx < E_ * C_; idx += 64)
      nz |= (__float_as_uint(b2[idx]) != 0u) ? 1 : 0;
    if (nz) atomicOr((int*)(auxsum + 22), 1);
  }
}

// ---------------- fused dense MoE FFN: r4 structure + setprio MFMA clusters ----
// 256 thr = 4 waves; 128 px/block; grid 512 = 2 blocks/CU (8 waves/CU = 2/SIMD).
// r4 post-mortem model: MFMA blocks its wave (no async MFMA) -> MFMA/VALU
// overlap requires the co-resident wave to be in a DIFFERENT phase. Both waves
// on a SIMD run identical code from equivalent barriers -> phase-locked ->
// per-SIMD time = MFMA(2048) + VALU(2200) + stalls = SUM, not max (= the
// measured 5900 cyc/super-iter). Fix attempt (T5): s_setprio(1) around the
// four pure-MFMA clusters per super-iter (G1A/G2A/G1B/G2B; G2 frag reads
// hoisted so clusters are register-only). Between-barrier region has 6
// sub-phases with no internal syncs, so waves CAN drift; setprio amplifies
// skew into stable anti-phase (MFMA-cluster wave wins issue; the other wave
// falls into its VALU phase). Everything else identical to r4 (216us-class).
__global__ __launch_bounds__(256, 2) void k_ffn(const unsigned short* __restrict__ xcl,
                                                const unsigned short* __restrict__ wimg,
                                                const unsigned short* __restrict__ b1h,
                                                const float* __restrict__ b2,
                                                const float* __restrict__ mask,
                                                const float* __restrict__ aux,
                                                const float* __restrict__ x,
                                                float* __restrict__ y){
  __shared__ unsigned char smem[65536];
  int tid = threadIdx.x;
  int w = tid >> 6, l = tid & 63;
  int l31 = l & 31, hi = l >> 5;
  int hi4 = hi * 4;
  int pix0 = blockIdx.x * 128;
  int off = (blockIdx.x % 11) * 16;
  const unsigned char* wimgB = (const unsigned char*)wimg;
  const unsigned char* b1hB  = (const unsigned char*)b1h;

  // aux loss (auxsum complete: k_pre stream-ordered before us)
  if (blockIdx.x == 0 && tid == 0){
    float s = 0.f;
    const float invN = 1.0f / (float)N_;
    for (int e = 0; e < E_; ++e)
      s += (aux[e] * invN) * (aux[E_ + e] * invN);
    y[(size_t)N_ * C_] = (float)E_ * s;
  }

  // X B-frags (32x32x16 f16): lane l: X^T[c = kc*16 + hi*8 + j][pix = 32w + l31]
  half8 Xf[8];
  {
    const unsigned short* xrow = xcl + ((size_t)(pix0 + w * 32 + l31) << 7) + hi * 8;
    #pragma unroll
    for (int kc = 0; kc < 8; ++kc)
      Xf[kc] = *(const half8*)(xrow + kc * 16);
  }

  uint4 bhA[4], bhB[4];
  const size_t mrow = (size_t)(pix0 + w * 32 + l31) * 11;

  // prologue: stage super-iter 0 (records off, off+1) into buffer 0
  {
    #pragma unroll
    for (int k = 0; k < 2; ++k){
      int rec = off + k;
      const unsigned char* gs = wimgB + (size_t)rec * 16384 + w * 4096 + l * 16;
      unsigned char* dst = smem + k * 16384 + w * 4096;
      GLD(gs, dst);               GLD(gs + 1024, dst + 1024);
      GLD(gs + 2048, dst + 2048); GLD(gs + 3072, dst + 3072);
    }
    #pragma unroll
    for (int k = 0; k < 2; ++k){
      int rec = off + k;
      const unsigned char* bp = b1hB + rec * 64 + hi * 32;
      bhA[2 * k]     = *(const uint4*)(bp);
      bhA[2 * k + 1] = *(const uint4*)(bp + 16);
    }
  }
  // routing-weight prefetch pipeline: wrn holds expert (off>>4)'s weight
  float wrn = mask[mrow + (off >> 4)];
  __syncthreads();   // full drain: buffer 0 + regs ready

  float16v facc[4];
  #pragma unroll
  for (int ct = 0; ct < 4; ++ct) facc[ct] = (float16v)0.0f;
  h2 wr2 = (h2)(_Float16)0.0f;

  // one record's compute: GEMM1(LDS W1) -> gelu/pack/pswap -> GEMM2(LDS W2)
  // MFMA clusters are pure-register (frag reads hoisted) and setprio(1)-wrapped.
#define REC_BODY(WB, BH0, BH1)                                                      \
  {                                                                                 \
    half8 a_[8];                                                                    \
    _Pragma("unroll")                                                               \
    for (int kc_ = 0; kc_ < 8; ++kc_)                                               \
      a_[kc_] = *(const half8*)((WB) + kc_ * 1024 + l * 16);                        \
    float16v hacc_ = (float16v)0.0f;                                                \
    __builtin_amdgcn_s_setprio(1);                                                  \
    _Pragma("unroll")                                                               \
    for (int kc_ = 0; kc_ < 8; ++kc_)                                               \
      hacc_ = __builtin_amdgcn_mfma_f32_32x32x16_f16(a_[kc_], Xf[kc_], hacc_, 0, 0, 0); \
    __builtin_amdgcn_s_setprio(0);                                                  \
    union { uint4 v[2]; h2 h[8]; } bu_;                                             \
    bu_.v[0] = BH0; bu_.v[1] = BH1;                                                 \
    unsigned pd_[8];                                                                \
    _Pragma("unroll")                                                               \
    for (int k_ = 0; k_ < 8; ++k_){                                                 \
      h2 v_ = pkrtz(hacc_[2 * k_], hacc_[2 * k_ + 1]);                              \
      v_ = v_ + bu_.h[k_];                                                          \
      union { h2 h; unsigned u; } g_;                                               \
      g_.h = gelu2h(v_, wr2);                                                       \
      pd_[k_] = g_.u;                                                               \
    }                                                                               \
    pswap32(pd_[0], pd_[2]); pswap32(pd_[1], pd_[3]);                               \
    pswap32(pd_[4], pd_[6]); pswap32(pd_[5], pd_[7]);                               \
    union { unsigned u[4]; half8 s; } cv0_, cv1_;                                   \
    cv0_.u[0] = pd_[0]; cv0_.u[1] = pd_[1]; cv0_.u[2] = pd_[2]; cv0_.u[3] = pd_[3]; \
    cv1_.u[0] = pd_[4]; cv1_.u[1] = pd_[5]; cv1_.u[2] = pd_[6]; cv1_.u[3] = pd_[7]; \
    half8 wv_[8];                                                                   \
    _Pragma("unroll")                                                               \
    for (int q_ = 0; q_ < 8; ++q_)                                                  \
      wv_[q_] = *(const half8*)((WB) + 8192 + q_ * 1024 + l * 16);                  \
    __builtin_amdgcn_s_setprio(1);                                                  \
    _Pragma("unroll")                                                               \
    for (int ct_ = 0; ct_ < 4; ++ct_){                                              \
      facc[ct_] = __builtin_amdgcn_mfma_f32_32x32x16_f16(wv_[2 * ct_],     cv0_.s, facc[ct_], 0, 0, 0); \
      facc[ct_] = __builtin_amdgcn_mfma_f32_32x32x16_f16(wv_[2 * ct_ + 1], cv1_.s, facc[ct_], 0, 0, 0); \
    }                                                                               \
    __builtin_amdgcn_s_setprio(0);                                                  \
  }

#define SUPER_BODY(J, BHC, BHL)                                                     \
  {                                                                                 \
    asm volatile("s_waitcnt vmcnt(4)" ::: "memory");                                \
    __builtin_amdgcn_s_barrier();                                                   \
    __builtin_amdgcn_sched_barrier(0);                                              \
    /* prefetch super-iter J+1: 8 GLDs first, then 4 bias loads; wrap benign */     \
    {                                                                               \
      unsigned char* dbuf_ = smem + ((((J) + 1) & 1) << 15);                        \
      _Pragma("unroll")                                                             \
      for (int k_ = 0; k_ < 2; ++k_){                                               \
        int rn_ = 2 * (J) + 2 + k_ + off; if (rn_ >= 176) rn_ -= 176;               \
        const unsigned char* gs_ = wimgB + (size_t)rn_ * 16384 + w * 4096 + l * 16; \
        unsigned char* dst_ = dbuf_ + k_ * 16384 + w * 4096;                        \
        GLD(gs_, dst_);               GLD(gs_ + 1024, dst_ + 1024);                 \
        GLD(gs_ + 2048, dst_ + 2048); GLD(gs_ + 3072, dst_ + 3072);                 \
      }                                                                             \
      __builtin_amdgcn_sched_barrier(0);                                            \
      _Pragma("unroll")                                                             \
      for (int k_ = 0; k_ < 2; ++k_){                                               \
        int rn_ = 2 * (J) + 2 + k_ + off; if (rn_ >= 176) rn_ -= 176;               \
        const unsigned char* bp_ = b1hB + rn_ * 64 + hi * 32;                       \
        BHL[2 * k_]     = *(const uint4*)(bp_);                                     \
        BHL[2 * k_ + 1] = *(const uint4*)(bp_ + 16);                                \
      }                                                                             \
    }                                                                               \
    __builtin_amdgcn_sched_barrier(0);                                              \
    if (((J) & 7) == 0){   /* expert switch every 8 super-iters (uniform) */        \
      _Float16 wh_ = (_Float16)wrn;                                                 \
      wr2 = (h2){wh_, wh_};                                                         \
      int rn_ = 2 * (J) + 16 + off; if (rn_ >= 176) rn_ -= 176;                     \
      wrn = mask[mrow + (rn_ >> 4)];                                                \
    }                                                                               \
    const unsigned char* wb_ = smem + (((J) & 1) << 15);                            \
    REC_BODY(wb_, BHC[0], BHC[1]);                                                  \
    REC_BODY(wb_ + 16384, BHC[2], BHC[3]);                                          \
  }

  #pragma unroll 1
  for (int jj = 0; jj < 44; ++jj){
    SUPER_BODY(2 * jj,     bhA, bhB);
    SUPER_BODY(2 * jj + 1, bhB, bhA);
  }
#undef SUPER_BODY
#undef REC_BODY

  // ---- epilogue: O^T is channel-major -> direct NCHW writes ----
  __syncthreads();   // full drain incl. trailing prefetches (target dead buffer)
  float* lds_t = (float*)smem;               // 128 ch x stride 33 fp32
  float* b2t   = (float*)(smem + 17408);     // [c][12], zero-padded
  for (int idx = tid; idx < 1536; idx += 256){
    int cc = idx / 12, ee = idx - cc * 12;
    b2t[idx] = (ee < 11) ? b2[ee * 128 + cc] : 0.f;
  }
  int b2nz = ((const int*)aux)[22];

  #pragma unroll 1
  for (int r = 0; r < 4; ++r){        // round r: pixels pix0 + r*32..+31 (wave r)
    __syncthreads();
    if (w == r){
      #pragma unroll
      for (int ct = 0; ct < 4; ++ct)
        #pragma unroll
        for (int rg = 0; rg < 16; ++rg)
          lds_t[(ct * 32 + (rg & 3) + 8 * (rg >> 2) + hi4) * 33 + l31] = facc[ct][rg];
    }
    __syncthreads();
    int c = tid >> 1, ph = (tid & 1) << 4;
    int pixg = pix0 + r * 32 + ph;
    size_t base = (size_t)(pixg >> 14) * CHW_ + (size_t)c * HW_ + (pixg & 16383);
    float av[16];
    #pragma unroll
    for (int k = 0; k < 16; ++k) av[k] = lds_t[c * 33 + ph + k];
    if (b2nz){
      #pragma unroll
      for (int k = 0; k < 16; ++k){
        const float* mr = mask + (size_t)(pixg + k) * 11;
        #pragma unroll
        for (int e = 0; e < 11; ++e) av[k] = fmaf(mr[e], b2t[c * 12 + e], av[k]);
      }
    }
    #pragma unroll
    for (int q = 0; q < 4; ++q){
      float4 xv = *(const float4*)(x + base + q * 4);
      float4 o = {av[4 * q] + xv.x, av[4 * q + 1] + xv.y,
                  av[4 * q + 2] + xv.z, av[4 * q + 3] + xv.w};
      *(float4*)(y + base + q * 4) = o;
    }
  }
}

extern "C" void kernel_launch(void* const* d_in, const int* in_sizes, int n_in,
                              void* d_out, int out_size, void* d_ws, size_t ws_size,
                              hipStream_t stream){
  const float* x  = (const float*)d_in[0];
  const float* gw = (const float*)d_in[1];
  const float* gb = (const float*)d_in[2];
  const float* w1 = (const float*)d_in[3];
  const float* b1 = (const float*)d_in[4];
  const float* w2 = (const float*)d_in[5];
  const float* b2 = (const float*)d_in[6];
  float* y = (float*)d_out;
  char* ws = (char*)d_ws;

  unsigned short* xcl  = (unsigned short*)ws;                   // 16,777,216 B
  unsigned short* wimg = (unsigned short*)(ws + 16777216);      //  2,883,584 B
  float* mask   = (float*)(ws + 19660800);                      //  2,883,584 B
  float* auxsum = (float*)(ws + 22544384);                      //         96 B
  unsigned short* b1h  = (unsigned short*)(ws + 22544480);      //     11,264 B

  hipLaunchKernelGGL(k_convert, dim3(726),  dim3(256), 0, stream, w1, w2, b1, wimg, b1h, auxsum);
  hipLaunchKernelGGL(k_pre,     dim3(1024), dim3(256), 0, stream, x, gw, gb, b2, xcl, mask, auxsum);
  hipLaunchKernelGGL(k_ffn,     dim3(512),  dim3(256), 0, stream, xcl, wimg, b1h, b2, mask, auxsum, x, y);
}

// Round 6
// 347.881 us; speedup vs baseline: 1.0204x; 1.0204x over previous
//
#include <hip/hip_runtime.h>
#include <stdint.h>

#define C_   128
#define HW_  16384
#define CHW_ (C_*HW_)
#define N_   65536
#define E_   11
#define K_   6
#define HID_ 512

typedef __attribute__((ext_vector_type(8))) _Float16 half8;
typedef __attribute__((ext_vector_type(2))) _Float16 h2;
typedef __attribute__((ext_vector_type(2))) __fp16 fp16v2;
typedef __attribute__((ext_vector_type(16))) float float16v;
typedef __attribute__((ext_vector_type(2))) unsigned uint2v;

// async global->LDS, 16B per lane; LDS dst is wave-uniform base + lane*16
#define GLD(g, s) __builtin_amdgcn_global_load_lds( \
    (const __attribute__((address_space(1))) unsigned int*)(uintptr_t)(g), \
    (__attribute__((address_space(3))) unsigned int*)(unsigned int)(uintptr_t)(s), 16, 0, 0)

// f32x2 -> packed f16 pair (RTZ), bitcast to _Float16 vector
__device__ __forceinline__ h2 pkrtz(float a, float b){
  union { fp16v2 f; h2 h; } u;
  u.f = __builtin_amdgcn_cvt_pkrtz(a, b);
  return u.h;
}
// gelu(v)*wr on packed f16 pairs: odd deg-7 erf fit (|t|<=2.5, max err ~2.4e-3).
__device__ __forceinline__ h2 gelu2h(h2 v, h2 wr2){
  h2 u = v * v;
  h2 s = u * (h2)(_Float16)(-0.00076957f) + (h2)(_Float16)(0.0147811f);
  s = s * u + (h2)(_Float16)(-0.126434f);
  s = s * u + (h2)(_Float16)(0.795742f);
  h2 p = v * s;
  h2 phi = p * (h2)(_Float16)(0.5f) + (h2)(_Float16)(0.5f);
  return v * wr2 * phi;
}
// lane l <-> lane l^32 exchange: a' = [a_lo, b_lo], b' = [a_hi, b_hi]
__device__ __forceinline__ void pswap32(unsigned &a, unsigned &b){
#if __has_builtin(__builtin_amdgcn_permlane32_swap)
  uint2v r = __builtin_amdgcn_permlane32_swap(a, b, false, false);
  a = r.x; b = r.y;
#else
  asm volatile("v_permlane32_swap_b32 %0, %1" : "+v"(a), "+v"(b));
#endif
}

// ---------------- build MFMA-frag-ordered f16 weight image (32x32x16 frags) ----
// record i = e*16+hc (16KB): [0,8KB) W1 A-frags kc=0..7: lane l holds
//   w1[e][hc*32+(l&31)][kc*16+(l>>5)*8 + j], j=0..7
// [8KB,16KB): W2 A-frags (ct*2+kc2): lane l: w2[e][ct*32+(l&31)][hc*32+kc2*16+(l>>5)*8+j]
// plus b1h image: per record 32 f16 in hacc-register order (j-order, hi-major).
__global__ __launch_bounds__(256) void k_convert(const float* __restrict__ w1,
                                                 const float* __restrict__ w2,
                                                 const float* __restrict__ b1,
                                                 unsigned short* __restrict__ wimg,
                                                 unsigned short* __restrict__ b1h,
                                                 float* __restrict__ auxsum){
  int t = blockIdx.x * 256 + threadIdx.x;
  if (t < 23) auxsum[t] = 0.0f;          // 22 aux accumulators + b2nz flag
  if (t >= 185856) return;
  if (t >= 180224){                       // b1h: 176 recs x 32 f16
    int t2 = t - 180224;
    int rec = t2 >> 5, j5 = t2 & 31;
    int hi = j5 >> 4, j = j5 & 15;
    int e = rec >> 4, hc = rec & 15;
    int row = (j & 3) + 8 * (j >> 2) + 4 * hi;
    union { _Float16 h; unsigned short u; } cv;
    cv.h = (_Float16)b1[e * 512 + hc * 32 + row];
    b1h[rec * 32 + j5] = cv.u;
    return;
  }
  const float* src;
  size_t dst;
  if (t < 90112){
    int e = t >> 13, hid = (t >> 4) & 511, c8 = t & 15;
    src = w1 + (size_t)t * 8;
    int rec = e * 16 + (hid >> 5);
    int kc = c8 >> 1, half = c8 & 1;
    int l = (hid & 31) | (half << 5);
    dst = (size_t)rec * 8192 + kc * 512 + l * 8;
  } else {
    int u = t - 90112;
    int e = u >> 13, cc = (u >> 6) & 127, hd8 = u & 63;
    src = w2 + (size_t)u * 8;
    int rec = e * 16 + (hd8 >> 2);
    int kc2 = (hd8 >> 1) & 1, half = hd8 & 1, ct = cc >> 5;
    int l = (cc & 31) | (half << 5);
    dst = (size_t)rec * 8192 + 4096 + (ct * 2 + kc2) * 512 + l * 8;
  }
  float4 a = *(const float4*)src, b = *(const float4*)(src + 4);
  union { _Float16 h[8]; uint4 v; } u4;
  u4.h[0] = (_Float16)a.x; u4.h[1] = (_Float16)a.y;
  u4.h[2] = (_Float16)a.z; u4.h[3] = (_Float16)a.w;
  u4.h[4] = (_Float16)b.x; u4.h[5] = (_Float16)b.y;
  u4.h[6] = (_Float16)b.z; u4.h[7] = (_Float16)b.w;
  *(uint4*)(wimg + dst) = u4.v;
}

// ---------------- fused: NCHW->channels-last f16 transpose + router ----------------
__global__ __launch_bounds__(256) void k_pre(const float* __restrict__ x,
                                             const float* __restrict__ gw,
                                             const float* __restrict__ gb,
                                             const float* __restrict__ b2,
                                             unsigned short* __restrict__ xcl,
                                             float* __restrict__ mask,
                                             float* __restrict__ auxsum){
  __shared__ __align__(16) float tt[64 * 130];
  __shared__ __align__(16) float g[E_ * C_];
  __shared__ float gbs[E_];
  __shared__ float ap[E_], al[E_];
  int tid = threadIdx.x;
  int pix0 = blockIdx.x * 64;
  int b = pix0 >> 14, hw0 = pix0 & 16383;
  const float* xb = x + (size_t)b * CHW_ + hw0;

  for (int i = tid; i < E_ * C_; i += 256) g[i] = gw[i];
  if (tid < E_) { gbs[tid] = gb[tid]; ap[tid] = 0.f; al[tid] = 0.f; }

  // float4 loads along the contiguous p axis: 4x fewer global trips than scalar
  #pragma unroll
  for (int it = 0; it < 8; ++it){
    int flat = it * 256 + tid;          // 2048 quads = 128 c x 16 quads-of-p
    int c = flat >> 4, p4 = (flat & 15) << 2;
    float4 v = *(const float4*)(xb + (size_t)c * HW_ + p4);
    tt[(p4 + 0) * 130 + c] = v.x;
    tt[(p4 + 1) * 130 + c] = v.y;
    tt[(p4 + 2) * 130 + c] = v.z;
    tt[(p4 + 3) * 130 + c] = v.w;
  }
  __syncthreads();
  #pragma unroll 4
  for (int it = 0; it < 16; ++it){
    int u = it * 256 + tid;
    int p = u >> 6, cc = u & 63;
    float f0 = tt[p * 130 + 2 * cc], f1 = tt[p * 130 + 2 * cc + 1];
    union { h2 h; unsigned u; } pv;
    pv.h = pkrtz(f0, f1);
    ((unsigned*)xcl)[(size_t)(pix0 + p) * 64 + cc] = pv.u;
  }

  // router: 4 threads per pixel (same wave quad), each 32 channels, float2 reads
  int p = tid >> 2, t4 = tid & 3;
  float lg[E_];
  #pragma unroll
  for (int e = 0; e < E_; ++e) lg[e] = (t4 == 0) ? gbs[e] : 0.f;
  const float2* ttrow = (const float2*)(tt + p * 130 + t4 * 32);
  #pragma unroll 4
  for (int j2 = 0; j2 < 16; ++j2){
    float2 xv = ttrow[j2];
    #pragma unroll
    for (int e = 0; e < E_; ++e){
      float2 gv = *(const float2*)(g + e * C_ + t4 * 32 + j2 * 2);
      lg[e] = fmaf(xv.x, gv.x, lg[e]);
      lg[e] = fmaf(xv.y, gv.y, lg[e]);
    }
  }
  #pragma unroll
  for (int e = 0; e < E_; ++e){
    lg[e] += __shfl_xor(lg[e], 1, 64);
    lg[e] += __shfl_xor(lg[e], 2, 64);
  }
  float mx = lg[0];
  #pragma unroll
  for (int e = 1; e < E_; ++e) mx = fmaxf(mx, lg[e]);
  float pr[E_]; float s = 0.f;
  #pragma unroll
  for (int e = 0; e < E_; ++e){ pr[e] = expf(lg[e] - mx); s += pr[e]; }
  float inv = 1.0f / s;
  #pragma unroll
  for (int e = 0; e < E_; ++e) pr[e] *= inv;

  unsigned selmask = 0; float wsum = 0.f;
  for (int k = 0; k < K_; ++k){
    float bv = -1.f; int bi = 0;
    #pragma unroll
    for (int e = 0; e < E_; ++e){
      bool better = (((selmask >> e) & 1u) == 0u) && (pr[e] > bv);
      bv = better ? pr[e] : bv;
      bi = better ? e : bi;
    }
    selmask |= 1u << bi; wsum += bv;
  }
  float invw = 1.0f / wsum;
  if (t4 == 0){
    int pix = pix0 + p;
    #pragma unroll
    for (int e = 0; e < E_; ++e){
      bool sel = (selmask >> e) & 1u;
      mask[(size_t)pix * E_ + e] = sel ? pr[e] * invw : 0.f;
      atomicAdd(&ap[e], pr[e]);
      if (sel) atomicAdd(&al[e], 1.0f);
    }
  }
  __syncthreads();
  if (tid < E_){
    atomicAdd(&auxsum[tid], ap[tid]);
    atomicAdd(&auxsum[E_ + tid], al[tid]);
  }
  // b2 nonzero flag (block 0 only; k_ffn runs after all k_pre blocks)
  if (blockIdx.x == 0 && tid < 64){
    int nz = 0;
    for (int idx = tid; idx < E_ * C_; idx += 64)
      nz |= (__float_as_uint(b2[idx]) != 0u) ? 1 : 0;
    if (nz) atomicOr((int*)(auxsum + 22), 1);
  }
}

// ---------------- fused dense MoE FFN: record-pipelined body + T19 interleave ----
// Container identical to r4 (217us-class): 256 thr = 4 waves, 128 px/block,
// grid 512 = 2 blocks/CU (8 waves/CU = 2/SIMD), same staging/barriers/ring.
// r5 model: in-order issue means a wave in an MFMA burst can't issue VALU, and
// both waves per SIMD are phase-locked -> time = MFMA(2048) + VALU(2200) +
// stalls = 5915 cyc/super-iter (sum, not max). Fix: put the VALU BETWEEN the
// MFMAs in each wave's instruction stream. Within a super-iter (records A,B):
//   R1: ds-read aA,aB; bare G1(A) chain (reads hide in its dep stalls)
//   R2: G1(B) chain INTERLEAVED with EPI(A)   [sched_group_barrier MFMA1:VALU11]
//   R3: wvA reads + G2(A) INTERLEAVED with EPI(B) [DS1:MFMA1:VALU11]
//   R4: wvB reads + bare G2(B)
// Deps: EPI(A)<-hA (R1 done); G2(A)<-cvA (R2 done); EPI(B)<-hB (R2 done). Same
// math, same accumulation order as r0/r4 -> bit-identical output expected.
// LDS-port floor for this layout: 256 ds_read_b128/CU/super-iter ~3072 cyc.
__global__ __launch_bounds__(256, 2) void k_ffn(const unsigned short* __restrict__ xcl,
                                                const unsigned short* __restrict__ wimg,
                                                const unsigned short* __restrict__ b1h,
                                                const float* __restrict__ b2,
                                                const float* __restrict__ mask,
                                                const float* __restrict__ aux,
                                                const float* __restrict__ x,
                                                float* __restrict__ y){
  __shared__ unsigned char smem[65536];
  int tid = threadIdx.x;
  int w = tid >> 6, l = tid & 63;
  int l31 = l & 31, hi = l >> 5;
  int hi4 = hi * 4;
  int pix0 = blockIdx.x * 128;
  int off = (blockIdx.x % 11) * 16;
  const unsigned char* wimgB = (const unsigned char*)wimg;
  const unsigned char* b1hB  = (const unsigned char*)b1h;

  // aux loss (auxsum complete: k_pre stream-ordered before us)
  if (blockIdx.x == 0 && tid == 0){
    float s = 0.f;
    const float invN = 1.0f / (float)N_;
    for (int e = 0; e < E_; ++e)
      s += (aux[e] * invN) * (aux[E_ + e] * invN);
    y[(size_t)N_ * C_] = (float)E_ * s;
  }

  // X B-frags (32x32x16 f16): lane l: X^T[c = kc*16 + hi*8 + j][pix = 32w + l31]
  half8 Xf[8];
  {
    const unsigned short* xrow = xcl + ((size_t)(pix0 + w * 32 + l31) << 7) + hi * 8;
    #pragma unroll
    for (int kc = 0; kc < 8; ++kc)
      Xf[kc] = *(const half8*)(xrow + kc * 16);
  }

  uint4 bhA[4], bhB[4];
  const size_t mrow = (size_t)(pix0 + w * 32 + l31) * 11;

  // prologue: stage super-iter 0 (records off, off+1) into buffer 0
  {
    #pragma unroll
    for (int k = 0; k < 2; ++k){
      int rec = off + k;
      const unsigned char* gs = wimgB + (size_t)rec * 16384 + w * 4096 + l * 16;
      unsigned char* dst = smem + k * 16384 + w * 4096;
      GLD(gs, dst);               GLD(gs + 1024, dst + 1024);
      GLD(gs + 2048, dst + 2048); GLD(gs + 3072, dst + 3072);
    }
    #pragma unroll
    for (int k = 0; k < 2; ++k){
      int rec = off + k;
      const unsigned char* bp = b1hB + rec * 64 + hi * 32;
      bhA[2 * k]     = *(const uint4*)(bp);
      bhA[2 * k + 1] = *(const uint4*)(bp + 16);
    }
  }
  // routing-weight prefetch pipeline: wrn holds expert (off>>4)'s weight
  float wrn = mask[mrow + (off >> 4)];
  __syncthreads();   // full drain: buffer 0 + regs ready

  float16v facc[4];
  #pragma unroll
  for (int ct = 0; ct < 4; ++ct) facc[ct] = (float16v)0.0f;
  h2 wr2 = (h2)(_Float16)0.0f;

  // bias + gelu + f16 pack + lane-half swap for one record -> cv pair
#define EPIC(HACC, BH0, BH1, CV0, CV1)                                              \
  {                                                                                 \
    union { uint4 v[2]; h2 h[8]; } bu_;                                             \
    bu_.v[0] = BH0; bu_.v[1] = BH1;                                                 \
    unsigned pd_[8];                                                                \
    _Pragma("unroll")                                                               \
    for (int k_ = 0; k_ < 8; ++k_){                                                 \
      h2 v_ = pkrtz(HACC[2 * k_], HACC[2 * k_ + 1]);                                \
      v_ = v_ + bu_.h[k_];                                                          \
      union { h2 h; unsigned u; } g_;                                               \
      g_.h = gelu2h(v_, wr2);                                                       \
      pd_[k_] = g_.u;                                                               \
    }                                                                               \
    pswap32(pd_[0], pd_[2]); pswap32(pd_[1], pd_[3]);                               \
    pswap32(pd_[4], pd_[6]); pswap32(pd_[5], pd_[7]);                               \
    union { unsigned u[4]; half8 s; } c0_, c1_;                                     \
    c0_.u[0] = pd_[0]; c0_.u[1] = pd_[1]; c0_.u[2] = pd_[2]; c0_.u[3] = pd_[3];     \
    c1_.u[0] = pd_[4]; c1_.u[1] = pd_[5]; c1_.u[2] = pd_[6]; c1_.u[3] = pd_[7];     \
    CV0 = c0_.s; CV1 = c1_.s;                                                       \
  }

#define SUPER_BODY(J, BHC, BHL)                                                     \
  {                                                                                 \
    asm volatile("s_waitcnt vmcnt(4)" ::: "memory");                                \
    __builtin_amdgcn_s_barrier();                                                   \
    __builtin_amdgcn_sched_barrier(0);                                              \
    /* prefetch super-iter J+1: 8 GLDs first, then 4 bias loads; wrap benign */     \
    {                                                                               \
      unsigned char* dbuf_ = smem + ((((J) + 1) & 1) << 15);                        \
      _Pragma("unroll")                                                             \
      for (int k_ = 0; k_ < 2; ++k_){                                               \
        int rn_ = 2 * (J) + 2 + k_ + off; if (rn_ >= 176) rn_ -= 176;               \
        const unsigned char* gs_ = wimgB + (size_t)rn_ * 16384 + w * 4096 + l * 16; \
        unsigned char* dst_ = dbuf_ + k_ * 16384 + w * 4096;                        \
        GLD(gs_, dst_);               GLD(gs_ + 1024, dst_ + 1024);                 \
        GLD(gs_ + 2048, dst_ + 2048); GLD(gs_ + 3072, dst_ + 3072);                 \
      }                                                                             \
      __builtin_amdgcn_sched_barrier(0);                                            \
      _Pragma("unroll")                                                             \
      for (int k_ = 0; k_ < 2; ++k_){                                               \
        int rn_ = 2 * (J) + 2 + k_ + off; if (rn_ >= 176) rn_ -= 176;               \
        const unsigned char* bp_ = b1hB + rn_ * 64 + hi * 32;                       \
        BHL[2 * k_]     = *(const uint4*)(bp_);                                     \
        BHL[2 * k_ + 1] = *(const uint4*)(bp_ + 16);                                \
      }                                                                             \
    }                                                                               \
    __builtin_amdgcn_sched_barrier(0);                                              \
    if (((J) & 7) == 0){   /* expert switch every 8 super-iters (uniform) */        \
      _Float16 wh_ = (_Float16)wrn;                                                 \
      wr2 = (h2){wh_, wh_};                                                         \
      int rn_ = 2 * (J) + 16 + off; if (rn_ >= 176) rn_ -= 176;                     \
      wrn = mask[mrow + (rn_ >> 4)];                                                \
    }                                                                               \
    const unsigned char* wb_ = smem + (((J) & 1) << 15);                            \
    /* ---- R1: frag reads + bare G1(A) chain (reads hide in dep stalls) ---- */    \
    half8 aA_[8], aB_[8];                                                           \
    _Pragma("unroll")                                                               \
    for (int q_ = 0; q_ < 8; ++q_){                                                 \
      aA_[q_] = *(const half8*)(wb_ + q_ * 1024 + l * 16);                          \
      aB_[q_] = *(const half8*)(wb_ + 16384 + q_ * 1024 + l * 16);                  \
    }                                                                               \
    float16v hA_ = (float16v)0.0f, hB_ = (float16v)0.0f;                            \
    _Pragma("unroll")                                                               \
    for (int kc_ = 0; kc_ < 8; ++kc_)                                               \
      hA_ = __builtin_amdgcn_mfma_f32_32x32x16_f16(aA_[kc_], Xf[kc_], hA_, 0, 0, 0);\
    __builtin_amdgcn_sched_barrier(0);                                              \
    /* ---- R2: G1(B) chain interleaved with EPI(A) ---- */                         \
    _Pragma("unroll")                                                               \
    for (int kc_ = 0; kc_ < 8; ++kc_)                                               \
      hB_ = __builtin_amdgcn_mfma_f32_32x32x16_f16(aB_[kc_], Xf[kc_], hB_, 0, 0, 0);\
    half8 cvA0_, cvA1_;                                                             \
    EPIC(hA_, BHC[0], BHC[1], cvA0_, cvA1_);                                        \
    _Pragma("unroll")                                                               \
    for (int i_ = 0; i_ < 8; ++i_){                                                 \
      __builtin_amdgcn_sched_group_barrier(0x008, 1, 0);   /* 1 MFMA  */            \
      __builtin_amdgcn_sched_group_barrier(0x002, 11, 0);  /* 11 VALU */            \
    }                                                                               \
    __builtin_amdgcn_sched_barrier(0);                                              \
    /* ---- R3: wvA reads + G2(A) interleaved with EPI(B) ---- */                   \
    half8 wvA_[8];                                                                  \
    _Pragma("unroll")                                                               \
    for (int q_ = 0; q_ < 8; ++q_)                                                  \
      wvA_[q_] = *(const half8*)(wb_ + 8192 + q_ * 1024 + l * 16);                  \
    half8 cvB0_, cvB1_;                                                             \
    EPIC(hB_, BHC[2], BHC[3], cvB0_, cvB1_);                                        \
    _Pragma("unroll")                                                               \
    for (int ct_ = 0; ct_ < 4; ++ct_){                                              \
      facc[ct_] = __builtin_amdgcn_mfma_f32_32x32x16_f16(wvA_[2 * ct_],     cvA0_, facc[ct_], 0, 0, 0); \
      facc[ct_] = __builtin_amdgcn_mfma_f32_32x32x16_f16(wvA_[2 * ct_ + 1], cvA1_, facc[ct_], 0, 0, 0); \
    }                                                                               \
    _Pragma("unroll")                                                               \
    for (int i_ = 0; i_ < 8; ++i_){                                                 \
      __builtin_amdgcn_sched_group_barrier(0x100, 1, 0);   /* 1 DS_READ */          \
      __builtin_amdgcn_sched_group_barrier(0x008, 1, 0);   /* 1 MFMA    */          \
      __builtin_amdgcn_sched_group_barrier(0x002, 11, 0);  /* 11 VALU   */          \
    }                                                                               \
    __builtin_amdgcn_sched_barrier(0);                                              \
    /* ---- R4: wvB reads + bare G2(B) ---- */                                      \
    half8 wvB_[8];                                                                  \
    _Pragma("unroll")                                                               \
    for (int q_ = 0; q_ < 8; ++q_)                                                  \
      wvB_[q_] = *(const half8*)(wb_ + 16384 + 8192 + q_ * 1024 + l * 16);          \
    _Pragma("unroll")                                                               \
    for (int ct_ = 0; ct_ < 4; ++ct_){                                              \
      facc[ct_] = __builtin_amdgcn_mfma_f32_32x32x16_f16(wvB_[2 * ct_],     cvB0_, facc[ct_], 0, 0, 0); \
      facc[ct_] = __builtin_amdgcn_mfma_f32_32x32x16_f16(wvB_[2 * ct_ + 1], cvB1_, facc[ct_], 0, 0, 0); \
    }                                                                               \
  }

  #pragma unroll 1
  for (int jj = 0; jj < 44; ++jj){
    SUPER_BODY(2 * jj,     bhA, bhB);
    SUPER_BODY(2 * jj + 1, bhB, bhA);
  }
#undef SUPER_BODY
#undef EPIC

  // ---- epilogue: O^T is channel-major -> direct NCHW writes ----
  __syncthreads();   // full drain incl. trailing prefetches (target dead buffer)
  float* lds_t = (float*)smem;               // 128 ch x stride 33 fp32
  float* b2t   = (float*)(smem + 17408);     // [c][12], zero-padded
  for (int idx = tid; idx < 1536; idx += 256){
    int cc = idx / 12, ee = idx - cc * 12;
    b2t[idx] = (ee < 11) ? b2[ee * 128 + cc] : 0.f;
  }
  int b2nz = ((const int*)aux)[22];

  #pragma unroll 1
  for (int r = 0; r < 4; ++r){        // round r: pixels pix0 + r*32..+31 (wave r)
    __syncthreads();
    if (w == r){
      #pragma unroll
      for (int ct = 0; ct < 4; ++ct)
        #pragma unroll
        for (int rg = 0; rg < 16; ++rg)
          lds_t[(ct * 32 + (rg & 3) + 8 * (rg >> 2) + hi4) * 33 + l31] = facc[ct][rg];
    }
    __syncthreads();
    int c = tid >> 1, ph = (tid & 1) << 4;
    int pixg = pix0 + r * 32 + ph;
    size_t base = (size_t)(pixg >> 14) * CHW_ + (size_t)c * HW_ + (pixg & 16383);
    float av[16];
    #pragma unroll
    for (int k = 0; k < 16; ++k) av[k] = lds_t[c * 33 + ph + k];
    if (b2nz){
      #pragma unroll
      for (int k = 0; k < 16; ++k){
        const float* mr = mask + (size_t)(pixg + k) * 11;
        #pragma unroll
        for (int e = 0; e < 11; ++e) av[k] = fmaf(mr[e], b2t[c * 12 + e], av[k]);
      }
    }
    #pragma unroll
    for (int q = 0; q < 4; ++q){
      float4 xv = *(const float4*)(x + base + q * 4);
      float4 o = {av[4 * q] + xv.x, av[4 * q + 1] + xv.y,
                  av[4 * q + 2] + xv.z, av[4 * q + 3] + xv.w};
      *(float4*)(y + base + q * 4) = o;
    }
  }
}

extern "C" void kernel_launch(void* const* d_in, const int* in_sizes, int n_in,
                              void* d_out, int out_size, void* d_ws, size_t ws_size,
                              hipStream_t stream){
  const float* x  = (const float*)d_in[0];
  const float* gw = (const float*)d_in[1];
  const float* gb = (const float*)d_in[2];
  const float* w1 = (const float*)d_in[3];
  const float* b1 = (const float*)d_in[4];
  const float* w2 = (const float*)d_in[5];
  const float* b2 = (const float*)d_in[6];
  float* y = (float*)d_out;
  char* ws = (char*)d_ws;

  unsigned short* xcl  = (unsigned short*)ws;                   // 16,777,216 B
  unsigned short* wimg = (unsigned short*)(ws + 16777216);      //  2,883,584 B
  float* mask   = (float*)(ws + 19660800);                      //  2,883,584 B
  float* auxsum = (float*)(ws + 22544384);                      //         96 B
  unsigned short* b1h  = (unsigned short*)(ws + 22544480);      //     11,264 B

  hipLaunchKernelGGL(k_convert, dim3(726),  dim3(256), 0, stream, w1, w2, b1, wimg, b1h, auxsum);
  hipLaunchKernelGGL(k_pre,     dim3(1024), dim3(256), 0, stream, x, gw, gb, b2, xcl, mask, auxsum);
  hipLaunchKernelGGL(k_ffn,     dim3(512),  dim3(256), 0, stream, xcl, wimg, b1h, b2, mask, auxsum, x, y);
}

// Round 7
// 308.827 us; speedup vs baseline: 1.1494x; 1.1265x over previous
//
#include <hip/hip_runtime.h>
#include <stdint.h>

#define C_   128
#define HW_  16384
#define CHW_ (C_*HW_)
#define N_   65536
#define E_   11
#define K_   6
#define HID_ 512

typedef __attribute__((ext_vector_type(8))) _Float16 half8;
typedef __attribute__((ext_vector_type(2))) _Float16 h2;
typedef __attribute__((ext_vector_type(2))) __fp16 fp16v2;
typedef __attribute__((ext_vector_type(16))) float float16v;
typedef __attribute__((ext_vector_type(2))) unsigned uint2v;

// async global->LDS, 16B per lane; LDS dst is wave-uniform base + lane*16
#define GLD(g, s) __builtin_amdgcn_global_load_lds( \
    (const __attribute__((address_space(1))) unsigned int*)(uintptr_t)(g), \
    (__attribute__((address_space(3))) unsigned int*)(unsigned int)(uintptr_t)(s), 16, 0, 0)

// f32x2 -> packed f16 pair (RTZ), bitcast to _Float16 vector
__device__ __forceinline__ h2 pkrtz(float a, float b){
  union { fp16v2 f; h2 h; } u;
  u.f = __builtin_amdgcn_cvt_pkrtz(a, b);
  return u.h;
}
// gelu(v)*wr on packed f16 pairs: odd deg-7 erf fit (|t|<=2.5, max err ~2.4e-3).
__device__ __forceinline__ h2 gelu2h(h2 v, h2 wr2){
  h2 u = v * v;
  h2 s = u * (h2)(_Float16)(-0.00076957f) + (h2)(_Float16)(0.0147811f);
  s = s * u + (h2)(_Float16)(-0.126434f);
  s = s * u + (h2)(_Float16)(0.795742f);
  h2 p = v * s;
  h2 phi = p * (h2)(_Float16)(0.5f) + (h2)(_Float16)(0.5f);
  return v * wr2 * phi;
}
// lane l <-> lane l^32 exchange: a' = [a_lo, b_lo], b' = [a_hi, b_hi]
__device__ __forceinline__ void pswap32(unsigned &a, unsigned &b){
#if __has_builtin(__builtin_amdgcn_permlane32_swap)
  uint2v r = __builtin_amdgcn_permlane32_swap(a, b, false, false);
  a = r.x; b = r.y;
#else
  asm volatile("v_permlane32_swap_b32 %0, %1" : "+v"(a), "+v"(b));
#endif
}

// ---------------- merged prep: weight-image convert + transpose/router ----------
// blocks [0,726): build MFMA-frag-ordered f16 weight image (32x32x16 frags).
//   record i = e*16+hc (16KB): [0,8KB) W1 A-frags kc=0..7: lane l holds
//   w1[e][hc*32+(l&31)][kc*16+(l>>5)*8+j]; [8KB,16KB): W2 A-frags.
//   b1h image: per record 32 f16 in hacc-register order.
// blocks [726,1750): NCHW->channels-last f16 transpose + router for 64 px.
// The two roles are independent -> one launch runs them CONCURRENTLY (was
// serialized as two kernels). Aux-loss accumulation: per-block partial rows
// part[e][pb] / part[11+e][pb] (NO global atomics -> no pre-zeroing, no
// cross-XCD contention); reduced by k_ffn block 0.
__global__ __launch_bounds__(256) void k_prep(const float* __restrict__ x,
                                              const float* __restrict__ gw,
                                              const float* __restrict__ gb,
                                              const float* __restrict__ w1,
                                              const float* __restrict__ w2,
                                              const float* __restrict__ b1,
                                              unsigned short* __restrict__ xcl,
                                              float* __restrict__ mask,
                                              unsigned short* __restrict__ wimg,
                                              unsigned short* __restrict__ b1h,
                                              float* __restrict__ part){
  __shared__ __align__(16) float tt[64 * 130];
  __shared__ __align__(16) float g[E_ * C_];
  __shared__ float gbs[E_];
  __shared__ float ap[E_], al[E_];

  if (blockIdx.x < 726){
    // ---- convert role ----
    int t = blockIdx.x * 256 + threadIdx.x;
    if (t >= 185856) return;
    if (t >= 180224){                       // b1h: 176 recs x 32 f16
      int t2 = t - 180224;
      int rec = t2 >> 5, j5 = t2 & 31;
      int hi = j5 >> 4, j = j5 & 15;
      int e = rec >> 4, hc = rec & 15;
      int row = (j & 3) + 8 * (j >> 2) + 4 * hi;
      union { _Float16 h; unsigned short u; } cv;
      cv.h = (_Float16)b1[e * 512 + hc * 32 + row];
      b1h[rec * 32 + j5] = cv.u;
      return;
    }
    const float* src;
    size_t dst;
    if (t < 90112){
      int e = t >> 13, hid = (t >> 4) & 511, c8 = t & 15;
      src = w1 + (size_t)t * 8;
      int rec = e * 16 + (hid >> 5);
      int kc = c8 >> 1, half = c8 & 1;
      int l = (hid & 31) | (half << 5);
      dst = (size_t)rec * 8192 + kc * 512 + l * 8;
    } else {
      int u = t - 90112;
      int e = u >> 13, cc = (u >> 6) & 127, hd8 = u & 63;
      src = w2 + (size_t)u * 8;
      int rec = e * 16 + (hd8 >> 2);
      int kc2 = (hd8 >> 1) & 1, half = hd8 & 1, ct = cc >> 5;
      int l = (cc & 31) | (half << 5);
      dst = (size_t)rec * 8192 + 4096 + (ct * 2 + kc2) * 512 + l * 8;
    }
    float4 a = *(const float4*)src, b = *(const float4*)(src + 4);
    union { _Float16 h[8]; uint4 v; } u4;
    u4.h[0] = (_Float16)a.x; u4.h[1] = (_Float16)a.y;
    u4.h[2] = (_Float16)a.z; u4.h[3] = (_Float16)a.w;
    u4.h[4] = (_Float16)b.x; u4.h[5] = (_Float16)b.y;
    u4.h[6] = (_Float16)b.z; u4.h[7] = (_Float16)b.w;
    *(uint4*)(wimg + dst) = u4.v;
    return;
  }

  // ---- pre role (transpose + router), r0-proven body ----
  int tid = threadIdx.x;
  int pb = blockIdx.x - 726;              // pre-block index 0..1023
  int pix0 = pb * 64;
  int b = pix0 >> 14, hw0 = pix0 & 16383;
  const float* xb = x + (size_t)b * CHW_ + hw0;

  for (int i = tid; i < E_ * C_; i += 256) g[i] = gw[i];
  if (tid < E_) { gbs[tid] = gb[tid]; ap[tid] = 0.f; al[tid] = 0.f; }

  #pragma unroll 4
  for (int it = 0; it < 32; ++it){
    int flat = it * 256 + tid;
    int c = flat >> 6, p = flat & 63;
    tt[p * 130 + c] = xb[c * HW_ + p];
  }
  __syncthreads();
  #pragma unroll 4
  for (int it = 0; it < 16; ++it){
    int u = it * 256 + tid;
    int p = u >> 6, cc = u & 63;
    float f0 = tt[p * 130 + 2 * cc], f1 = tt[p * 130 + 2 * cc + 1];
    union { h2 h; unsigned u; } pv;
    pv.h = pkrtz(f0, f1);
    ((unsigned*)xcl)[(size_t)(pix0 + p) * 64 + cc] = pv.u;
  }

  // router: 4 threads per pixel (same wave quad), each 32 channels, float2 reads
  int p = tid >> 2, t4 = tid & 3;
  float lg[E_];
  #pragma unroll
  for (int e = 0; e < E_; ++e) lg[e] = (t4 == 0) ? gbs[e] : 0.f;
  const float2* ttrow = (const float2*)(tt + p * 130 + t4 * 32);
  #pragma unroll 4
  for (int j2 = 0; j2 < 16; ++j2){
    float2 xv = ttrow[j2];
    #pragma unroll
    for (int e = 0; e < E_; ++e){
      float2 gv = *(const float2*)(g + e * C_ + t4 * 32 + j2 * 2);
      lg[e] = fmaf(xv.x, gv.x, lg[e]);
      lg[e] = fmaf(xv.y, gv.y, lg[e]);
    }
  }
  #pragma unroll
  for (int e = 0; e < E_; ++e){
    lg[e] += __shfl_xor(lg[e], 1, 64);
    lg[e] += __shfl_xor(lg[e], 2, 64);
  }
  float mx = lg[0];
  #pragma unroll
  for (int e = 1; e < E_; ++e) mx = fmaxf(mx, lg[e]);
  float pr[E_]; float s = 0.f;
  #pragma unroll
  for (int e = 0; e < E_; ++e){ pr[e] = expf(lg[e] - mx); s += pr[e]; }
  float inv = 1.0f / s;
  #pragma unroll
  for (int e = 0; e < E_; ++e) pr[e] *= inv;

  unsigned selmask = 0; float wsum = 0.f;
  for (int k = 0; k < K_; ++k){
    float bv = -1.f; int bi = 0;
    #pragma unroll
    for (int e = 0; e < E_; ++e){
      bool better = (((selmask >> e) & 1u) == 0u) && (pr[e] > bv);
      bv = better ? pr[e] : bv;
      bi = better ? e : bi;
    }
    selmask |= 1u << bi; wsum += bv;
  }
  float invw = 1.0f / wsum;
  if (t4 == 0){
    int pix = pix0 + p;
    #pragma unroll
    for (int e = 0; e < E_; ++e){
      bool sel = (selmask >> e) & 1u;
      mask[(size_t)pix * E_ + e] = sel ? pr[e] * invw : 0.f;
      atomicAdd(&ap[e], pr[e]);
      if (sel) atomicAdd(&al[e], 1.0f);
    }
  }
  __syncthreads();
  if (tid < E_){                 // per-block partial rows (no global atomics)
    part[tid * 1024 + pb]        = ap[tid];
    part[(E_ + tid) * 1024 + pb] = al[tid];
  }
}

// ---------------- fused dense MoE FFN: r0 body (216us best-measured) -----------
// 512 thr = 8 waves; 256 pixels/block; grid 256 = 1 block/CU (2 waves/SIMD).
// Wave w owns pixels pix0+32w..+31. 88 super-iters x 2 records (expert
// ring-swizzled start off=(blockIdx%11)*16 -- expert sum is order-invariant).
// W record (16KB) staged ONCE per CU via GLD; each wave reads frags from LDS.
// H: C->B layout via v_permlane32_swap (no LDS). LDS 64KB = 2 super-buffers.
// Staging order: all GLDs issued BEFORE the bias loads, so vmcnt(4) (4 newest
// outstanding = the 4 bias register loads) provably drains every GLD (r4-
// verified neutral). Schedule arc closed: barrier-split/setprio/SGB/record-
// pipeline all null or negative (r4/r5/r6) -- body kept verbatim from r0.
__global__ __launch_bounds__(512, 2) void k_ffn(const unsigned short* __restrict__ xcl,
                                                const unsigned short* __restrict__ wimg,
                                                const unsigned short* __restrict__ b1h,
                                                const float* __restrict__ b2,
                                                const float* __restrict__ mask,
                                                const float* __restrict__ aux,
                                                const float* __restrict__ x,
                                                float* __restrict__ y){
  __shared__ unsigned char smem[65536];
  __shared__ int b2f;
  int tid = threadIdx.x;
  int w = tid >> 6, l = tid & 63;
  int l31 = l & 31, hi = l >> 5;
  int hi4 = hi * 4;
  int pix0 = blockIdx.x * 256;
  int off = (blockIdx.x % 11) * 16;
  const unsigned char* wimgB = (const unsigned char*)wimg;
  const unsigned char* b1hB  = (const unsigned char*)b1h;

  if (tid == 0) b2f = 0;

  // aux loss: reduce k_prep's per-block partial rows (wave 0 of block 0 only;
  // ~4us, the one-block/CU straggler cost is bounded by this).
  if (blockIdx.x == 0 && w == 0){
    float s = 0.f;
    const float invN = 1.0f / (float)N_;
    for (int e = 0; e < E_; ++e){
      float pa = 0.f, pl = 0.f;
      #pragma unroll
      for (int i = 0; i < 16; ++i){
        pa += aux[e * 1024 + i * 64 + l];
        pl += aux[(E_ + e) * 1024 + i * 64 + l];
      }
      #pragma unroll
      for (int o = 32; o; o >>= 1){
        pa += __shfl_down(pa, o);
        pl += __shfl_down(pl, o);
      }
      if (l == 0) s += (pa * invN) * (pl * invN);
    }
    if (l == 0) y[(size_t)N_ * C_] = (float)E_ * s;
  }

  // X B-frags (32x32x16 f16): lane l: X^T[c = kc*16 + hi*8 + j][pix = 32w + l31]
  half8 Xf[8];
  {
    const unsigned short* xrow = xcl + ((size_t)(pix0 + w * 32 + l31) << 7) + hi * 8;
    #pragma unroll
    for (int kc = 0; kc < 8; ++kc)
      Xf[kc] = *(const half8*)(xrow + kc * 16);
  }

  uint4 bhA[4], bhB[4];
  const size_t mrow = (size_t)(pix0 + w * 32 + l31) * 11;

  // prologue: stage super-iter 0 (records off, off+1) into buffer 0.
  // GLDs first, then bias loads (vmcnt-order discipline).
  {
    #pragma unroll
    for (int k = 0; k < 2; ++k){
      int rec = off + k;
      const unsigned char* gs = wimgB + (size_t)rec * 16384 + w * 2048 + l * 16;
      unsigned char* dst = smem + k * 16384 + w * 2048;
      GLD(gs, dst);
      GLD(gs + 1024, dst + 1024);
    }
    #pragma unroll
    for (int k = 0; k < 2; ++k){
      const unsigned char* bp = b1hB + (off + k) * 64 + hi * 32;
      bhA[2 * k]     = *(const uint4*)(bp);
      bhA[2 * k + 1] = *(const uint4*)(bp + 16);
    }
  }
  // routing-weight prefetch pipeline: wrn holds expert (off>>4)'s weight
  float wrn = mask[mrow + (off >> 4)];
  __syncthreads();   // full drain: buffer 0 + regs ready

  float16v facc[4];
  #pragma unroll
  for (int ct = 0; ct < 4; ++ct) facc[ct] = (float16v)0.0f;
  h2 wr2 = (h2)(_Float16)0.0f;

  // one record's compute: GEMM1(LDS W1) -> gelu/pack/pswap -> GEMM2(LDS W2)
#define REC_BODY(WB, BH0, BH1)                                                      \
  {                                                                                 \
    float16v hacc_ = (float16v)0.0f;                                                \
    _Pragma("unroll")                                                               \
    for (int kc_ = 0; kc_ < 8; ++kc_){                                              \
      half8 a_ = *(const half8*)((WB) + kc_ * 1024 + l * 16);                       \
      hacc_ = __builtin_amdgcn_mfma_f32_32x32x16_f16(a_, Xf[kc_], hacc_, 0, 0, 0);  \
    }                                                                               \
    union { uint4 v[2]; h2 h[8]; } bu_;                                             \
    bu_.v[0] = BH0; bu_.v[1] = BH1;                                                 \
    unsigned pd_[8];                                                                \
    _Pragma("unroll")                                                               \
    for (int k_ = 0; k_ < 8; ++k_){                                                 \
      h2 v_ = pkrtz(hacc_[2 * k_], hacc_[2 * k_ + 1]);                              \
      v_ = v_ + bu_.h[k_];                                                          \
      union { h2 h; unsigned u; } g_;                                               \
      g_.h = gelu2h(v_, wr2);                                                       \
      pd_[k_] = g_.u;                                                               \
    }                                                                               \
    pswap32(pd_[0], pd_[2]); pswap32(pd_[1], pd_[3]);                               \
    pswap32(pd_[4], pd_[6]); pswap32(pd_[5], pd_[7]);                               \
    union { unsigned u[4]; half8 s; } cv0_, cv1_;                                   \
    cv0_.u[0] = pd_[0]; cv0_.u[1] = pd_[1]; cv0_.u[2] = pd_[2]; cv0_.u[3] = pd_[3]; \
    cv1_.u[0] = pd_[4]; cv1_.u[1] = pd_[5]; cv1_.u[2] = pd_[6]; cv1_.u[3] = pd_[7]; \
    _Pragma("unroll")                                                               \
    for (int ct_ = 0; ct_ < 4; ++ct_){                                              \
      half8 a0_ = *(const half8*)((WB) + 8192 + (ct_ * 2 + 0) * 1024 + l * 16);     \
      half8 a1_ = *(const half8*)((WB) + 8192 + (ct_ * 2 + 1) * 1024 + l * 16);     \
      facc[ct_] = __builtin_amdgcn_mfma_f32_32x32x16_f16(a0_, cv0_.s, facc[ct_], 0, 0, 0); \
      facc[ct_] = __builtin_amdgcn_mfma_f32_32x32x16_f16(a1_, cv1_.s, facc[ct_], 0, 0, 0); \
    }                                                                               \
  }

#define SUPER_BODY(J, BHC, BHL)                                                     \
  {                                                                                 \
    asm volatile("s_waitcnt vmcnt(4)" ::: "memory");                                \
    __builtin_amdgcn_s_barrier();                                                   \
    __builtin_amdgcn_sched_barrier(0);                                              \
    /* prefetch super-iter J+1: 4 GLDs FIRST, then 4 bias loads; wrap benign */     \
    {                                                                               \
      unsigned char* dbuf_ = smem + ((((J) + 1) & 1) << 15);                        \
      _Pragma("unroll")                                                             \
      for (int k_ = 0; k_ < 2; ++k_){                                               \
        int rn_ = 2 * (J) + 2 + k_ + off; if (rn_ >= 176) rn_ -= 176;               \
        const unsigned char* gs_ = wimgB + (size_t)rn_ * 16384 + w * 2048 + l * 16; \
        unsigned char* dst_ = dbuf_ + k_ * 16384 + w * 2048;                        \
        GLD(gs_, dst_);                                                             \
        GLD(gs_ + 1024, dst_ + 1024);                                               \
      }                                                                             \
      __builtin_amdgcn_sched_barrier(0);                                            \
      _Pragma("unroll")                                                             \
      for (int k_ = 0; k_ < 2; ++k_){                                               \
        int rn_ = 2 * (J) + 2 + k_ + off; if (rn_ >= 176) rn_ -= 176;               \
        const unsigned char* bp_ = b1hB + rn_ * 64 + hi * 32;                       \
        BHL[2 * k_]     = *(const uint4*)(bp_);                                     \
        BHL[2 * k_ + 1] = *(const uint4*)(bp_ + 16);                                \
      }                                                                             \
    }                                                                               \
    __builtin_amdgcn_sched_barrier(0);                                              \
    if (((J) & 7) == 0){   /* expert switch every 8 super-iters (uniform) */        \
      _Float16 wh_ = (_Float16)wrn;                                                 \
      wr2 = (h2){wh_, wh_};                                                         \
      int rn_ = 2 * (J) + 16 + off; if (rn_ >= 176) rn_ -= 176;                     \
      wrn = mask[mrow + (rn_ >> 4)];                                                \
    }                                                                               \
    const unsigned char* wb_ = smem + (((J) & 1) << 15);                            \
    REC_BODY(wb_, BHC[0], BHC[1]);                                                  \
    REC_BODY(wb_ + 16384, BHC[2], BHC[3]);                                          \
  }

  #pragma unroll 1
  for (int jj = 0; jj < 44; ++jj){
    SUPER_BODY(2 * jj,     bhA, bhB);
    SUPER_BODY(2 * jj + 1, bhB, bhA);
  }
#undef SUPER_BODY
#undef REC_BODY

  // ---- epilogue: O^T is channel-major -> direct NCHW writes ----
  __syncthreads();   // full drain incl. trailing prefetches (target dead buffer)
  float* lds_t = (float*)smem;               // 128 ch x stride 33 fp32
  float* b2t   = (float*)(smem + 17408);     // [c][12], zero-padded
  for (int idx = tid; idx < 1536; idx += 512){
    int cc = idx / 12, ee = idx - cc * 12;
    float v = (ee < 11) ? b2[ee * 128 + cc] : 0.f;
    b2t[idx] = v;
    if (v != 0.f) atomicOr(&b2f, 1);   // local b2-nonzero flag (no global pass)
  }
  __syncthreads();
  int b2nz = b2f;

  #pragma unroll 1
  for (int h = 0; h < 8; ++h){
    __syncthreads();
    if (w == h){
      #pragma unroll
      for (int ct = 0; ct < 4; ++ct)
        #pragma unroll
        for (int r = 0; r < 16; ++r)
          lds_t[(ct * 32 + (r & 3) + 8 * (r >> 2) + hi4) * 33 + l31] = facc[ct][r];
    }
    __syncthreads();
    int c = tid >> 2, p8 = (tid & 3) << 3;
    int pixg = pix0 + h * 32 + p8;
    size_t base = (size_t)(pixg >> 14) * CHW_ + (size_t)c * HW_ + (pixg & 16383);
    float av[8];
    #pragma unroll
    for (int k = 0; k < 8; ++k) av[k] = lds_t[c * 33 + p8 + k];
    if (b2nz){
      #pragma unroll
      for (int k = 0; k < 8; ++k){
        const float* mr = mask + (size_t)(pixg + k) * 11;
        #pragma unroll
        for (int e = 0; e < 11; ++e) av[k] = fmaf(mr[e], b2t[c * 12 + e], av[k]);
      }
    }
    float4 xv0 = *(const float4*)(x + base);
    float4 xv1 = *(const float4*)(x + base + 4);
    float4 o0 = {av[0] + xv0.x, av[1] + xv0.y, av[2] + xv0.z, av[3] + xv0.w};
    float4 o1 = {av[4] + xv1.x, av[5] + xv1.y, av[6] + xv1.z, av[7] + xv1.w};
    *(float4*)(y + base) = o0;
    *(float4*)(y + base + 4) = o1;
  }
}

extern "C" void kernel_launch(void* const* d_in, const int* in_sizes, int n_in,
                              void* d_out, int out_size, void* d_ws, size_t ws_size,
                              hipStream_t stream){
  const float* x  = (const float*)d_in[0];
  const float* gw = (const float*)d_in[1];
  const float* gb = (const float*)d_in[2];
  const float* w1 = (const float*)d_in[3];
  const float* b1 = (const float*)d_in[4];
  const float* w2 = (const float*)d_in[5];
  const float* b2 = (const float*)d_in[6];
  float* y = (float*)d_out;
  char* ws = (char*)d_ws;

  unsigned short* xcl  = (unsigned short*)ws;                   // 16,777,216 B
  unsigned short* wimg = (unsigned short*)(ws + 16777216);      //  2,883,584 B
  float* mask   = (float*)(ws + 19660800);                      //  2,883,584 B
  float* part   = (float*)(ws + 22544384);                      //     90,112 B (22x1024 partials)
  unsigned short* b1h  = (unsigned short*)(ws + 22634496);      //     11,264 B

  hipLaunchKernelGGL(k_prep, dim3(1750), dim3(256), 0, stream,
                     x, gw, gb, w1, w2, b1, xcl, mask, wimg, b1h, part);
  hipLaunchKernelGGL(k_ffn,  dim3(256),  dim3(512), 0, stream,
                     xcl, wimg, b1h, b2, mask, part, x, y);
}